// Round 4
// baseline (232.876 us; speedup 1.0000x reference)
//
#include <hip/hip_runtime.h>

typedef unsigned short u16;
typedef __attribute__((ext_vector_type(4))) float f32x4;
typedef __attribute__((ext_vector_type(8))) __bf16 bf16x8;
typedef __attribute__((ext_vector_type(8))) unsigned short us8;

#define NN (2048ull*2048ull)

__device__ __forceinline__ u16 f2b(float x){
  union { float f; unsigned u; } v; v.f = x;
  unsigned r = v.u + 0x7FFFu + ((v.u >> 16) & 1u);
  return (u16)(r >> 16);
}
__device__ __forceinline__ float b2f(u16 x){
  union { unsigned u; float f; } v; v.u = ((unsigned)x) << 16; return v.f;
}

// ---------------- fused 3-way mix of A -> A1 (row-major) + A2T, BT (transposed), bf16
//                  block(0,0) also zero-inits deg1/deg2/rowsum (replaces memset) -------
__global__ __launch_bounds__(256)
void k_mix(const float* __restrict__ A,
           const float* __restrict__ w1, const float* __restrict__ w2,
           const float* __restrict__ wl,
           u16* __restrict__ A1, u16* __restrict__ A2T, u16* __restrict__ BT,
           float* __restrict__ zbuf){
  __shared__ u16 lt[4][64][72];
  const int t = threadIdx.x;
  if (blockIdx.x == 0 && blockIdx.y == 0){
    #pragma unroll
    for (int i=0;i<48;i++) zbuf[i*256 + t] = 0.f;   // deg1,deg2,rowsum = 12288 floats
  }
  const int mq = t & 15, nr = t >> 4;
  const int n0 = blockIdx.y * 64, m0 = blockIdx.x * 64;
  float f[3][2][5];
  #pragma unroll
  for (int s=0;s<3;s++){
    const float* w = (s==0) ? w1 : (s==1) ? w2 : wl;
    #pragma unroll
    for (int c=0;c<2;c++){
      float m = -1e30f;
      #pragma unroll
      for (int e=0;e<5;e++) m = fmaxf(m, w[e*2+c]);
      float sum = 0.f;
      #pragma unroll
      for (int e=0;e<5;e++){ f[s][c][e] = __expf(w[e*2+c]-m); sum += f[s][c][e]; }
      float inv = 1.f/sum;
      #pragma unroll
      for (int e=0;e<5;e++) f[s][c][e] *= inv;
    }
  }

  #pragma unroll
  for (int rr=0; rr<4; ++rr){
    const int nl = nr*4 + rr;
    const size_t off = (size_t)(n0+nl)*2048 + m0 + mq*4;
    float4 a0 = *(const float4*)&A[off];
    float4 a1 = *(const float4*)&A[NN + off];
    float4 a2 = *(const float4*)&A[2*NN + off];
    float4 a3 = *(const float4*)&A[3*NN + off];
    float4 a4 = *(const float4*)&A[4*NN + off];
    float ax[4][5] = {{a0.x,a1.x,a2.x,a3.x,a4.x},
                      {a0.y,a1.y,a2.y,a3.y,a4.y},
                      {a0.z,a1.z,a2.z,a3.z,a4.z},
                      {a0.w,a1.w,a2.w,a3.w,a4.w}};
    #pragma unroll
    for (int c=0;c<2;c++){
      ushort4 o1, o2, o3;
      #pragma unroll
      for (int j=0;j<4;j++){
        float s1=0.f,s2=0.f,s3=0.f;
        #pragma unroll
        for (int e=0;e<5;e++){
          s1 += ax[j][e]*f[0][c][e];
          s2 += ax[j][e]*f[1][c][e];
          s3 += ax[j][e]*f[2][c][e];
        }
        ((u16*)&o1)[j] = f2b(s1);
        ((u16*)&o2)[j] = f2b(s2);
        ((u16*)&o3)[j] = f2b(s3);
      }
      *(ushort4*)&A1[(size_t)c*NN + off] = o1;
      *(ushort4*)&lt[c][nl][mq*4] = o2;
      *(ushort4*)&lt[2+c][nl][mq*4] = o3;
    }
  }
  __syncthreads();
  const int nq = t & 15, mr = t >> 4;
  #pragma unroll
  for (int s=0;s<4;s++){
    u16* __restrict__ dst = (s<2) ? A2T : BT;
    const int c = s & 1;
    #pragma unroll
    for (int rr=0;rr<4;rr++){
      const int ml = mr*4 + rr;
      ushort4 o;
      o.x = lt[s][nq*4+0][ml];
      o.y = lt[s][nq*4+1][ml];
      o.z = lt[s][nq*4+2][ml];
      o.w = lt[s][nq*4+3][ml];
      *(ushort4*)&dst[(size_t)c*NN + (size_t)(m0+ml)*2048 + n0 + nq*4] = o;
    }
  }
}

// ------- big bt-GEMM (m97 2-barrier loop, BK=128): C = A @ Bt^T (bf16 out)
//         + fused column sums ------------------------------------------------------
__global__ __launch_bounds__(256, 2)
void k_gemm_big(const u16* __restrict__ A, const u16* __restrict__ Bt,
                u16* __restrict__ C, float* __restrict__ deg){
  __shared__ u16 lA[128*128];
  __shared__ u16 lB[128*128];
  const int tid = threadIdx.x;
  const int bm = blockIdx.x, bn = blockIdx.y, cc = blockIdx.z;
  const u16* __restrict__ Ab = A + (size_t)cc*NN + (size_t)(bm*128)*2048;
  const u16* __restrict__ Bb = Bt + (size_t)cc*NN + (size_t)(bn*128)*2048;
  const int wid = tid >> 6, lane = tid & 63;
  const int wr = wid >> 1, wc = wid & 1;
  const int fl = lane & 15, fk = (lane >> 4) << 3;
  const int srow = (wid << 2) + (lane >> 4);      // 0..15 within a 16-row stage chunk
  const int scol = (lane & 15) << 3;              // 0..120 (u16 elems)

  f32x4 acc[4][4];
  const f32x4 zero = {0.f,0.f,0.f,0.f};
  #pragma unroll
  for (int i=0;i<4;i++)
    #pragma unroll
    for (int jj=0;jj<4;jj++) acc[i][jj] = zero;

  for (int k0 = 0; k0 < 2048; k0 += 128){
    #pragma unroll
    for (int it = 0; it < 8; ++it){
      int r = it*16 + srow;
      __builtin_amdgcn_global_load_lds(
        (const __attribute__((address_space(1))) void*)(Ab + (size_t)r*2048 + k0 + scol),
        (__attribute__((address_space(3))) void*)(&lA[(it*16 + (wid<<2))*128]), 16, 0, 0);
      __builtin_amdgcn_global_load_lds(
        (const __attribute__((address_space(1))) void*)(Bb + (size_t)r*2048 + k0 + scol),
        (__attribute__((address_space(3))) void*)(&lB[(it*16 + (wid<<2))*128]), 16, 0, 0);
    }
    __syncthreads();
    #pragma unroll
    for (int ks = 0; ks < 4; ++ks){
      bf16x8 af[4], bfr[4];
      #pragma unroll
      for (int mi=0;mi<4;mi++)
        af[mi] = *reinterpret_cast<const bf16x8*>(&lA[(wr*64 + mi*16 + fl)*128 + ks*32 + fk]);
      #pragma unroll
      for (int ni=0;ni<4;ni++)
        bfr[ni] = *reinterpret_cast<const bf16x8*>(&lB[(wc*64 + ni*16 + fl)*128 + ks*32 + fk]);
      #pragma unroll
      for (int mi=0;mi<4;mi++)
        #pragma unroll
        for (int ni=0;ni<4;ni++)
          acc[mi][ni] = __builtin_amdgcn_mfma_f32_16x16x32_bf16(af[mi], bfr[ni], acc[mi][ni], 0, 0, 0);
    }
    __syncthreads();
  }

  // fused column sums: deg[c][col] += sum over this block's 128 rows
  #pragma unroll
  for (int ni=0; ni<4; ++ni){
    float cs = 0.f;
    #pragma unroll
    for (int mi=0;mi<4;mi++)
      #pragma unroll
      for (int r=0;r<4;r++) cs += acc[mi][ni][r];
    cs += __shfl_xor(cs, 16);
    cs += __shfl_xor(cs, 32);
    if (lane < 16)
      atomicAdd(&deg[cc*2048 + bn*128 + wc*64 + ni*16 + fl], cs);
  }
  // bf16 C store
  u16* __restrict__ Cb = C + (size_t)cc*NN + (size_t)(bm*128 + wr*64)*2048 + bn*128 + wc*64;
  const int rbase = (lane >> 4) << 2;
  #pragma unroll
  for (int mi=0;mi<4;mi++)
    #pragma unroll
    for (int ni=0;ni<4;ni++)
      #pragma unroll
      for (int r=0;r<4;r++)
        Cb[(size_t)(mi*16 + rbase + r)*2048 + ni*16 + fl] = f2b(acc[mi][ni][r]);
}

// ---------------- BT *= dinv1[k] in place ----------------
__global__ void k_btscale(u16* __restrict__ BT, const float* __restrict__ deg){
  size_t idx = (size_t)blockIdx.x*256 + threadIdx.x;   // 2*NN/8 = 1,048,576 total
  int c  = (int)(idx >> 19);
  int k8 = ((int)(idx & 255)) * 8;
  us8 v = ((const us8*)BT)[idx];
  #pragma unroll
  for (int j=0;j<8;j++){
    float d = deg[c*2048 + k8 + j];
    float di = d > 0.f ? 1.f/d : 0.f;
    v[j] = f2b(b2f(v[j]) * di);
  }
  ((us8*)BT)[idx] = v;
}

// -------- normalize (dinv2[col]) + transpose -> HT bf16 + rowsum atomics --------------
__global__ __launch_bounds__(256)
void k_ntrans(const u16* __restrict__ H2, const float* __restrict__ deg2,
              u16* __restrict__ HT, float* __restrict__ rowsum){
  __shared__ u16 lt[64][72];
  const int t = threadIdx.x;
  const int mq = t & 15, nr = t >> 4;
  const int n0 = blockIdx.y*64, m0 = blockIdx.x*64, c = blockIdx.z;
  float di[4];
  #pragma unroll
  for (int j=0;j<4;j++){
    float d = deg2[c*2048 + m0 + mq*4 + j];
    di[j] = d > 0.f ? 1.f/d : 0.f;
  }
  float rp[4];
  #pragma unroll
  for (int rr=0;rr<4;rr++){
    const int nl = nr*4 + rr;
    ushort4 hv = *(const ushort4*)&H2[(size_t)c*NN + (size_t)(n0+nl)*2048 + m0 + mq*4];
    float v0 = b2f(hv.x)*di[0], v1 = b2f(hv.y)*di[1], v2 = b2f(hv.z)*di[2], v3 = b2f(hv.w)*di[3];
    rp[rr] = v0+v1+v2+v3;
    ushort4 o; o.x=f2b(v0); o.y=f2b(v1); o.z=f2b(v2); o.w=f2b(v3);
    *(ushort4*)&lt[nl][mq*4] = o;
  }
  #pragma unroll
  for (int rr=0;rr<4;rr++){
    float s = rp[rr];
    s += __shfl_xor(s, 1); s += __shfl_xor(s, 2);
    s += __shfl_xor(s, 4); s += __shfl_xor(s, 8);
    if (mq == 0) atomicAdd(&rowsum[c*2048 + n0 + nr*4 + rr], s);
  }
  __syncthreads();
  const int nq = t & 15, mr = t >> 4;
  #pragma unroll
  for (int rr=0;rr<4;rr++){
    const int ml = mr*4 + rr;
    ushort4 o;
    o.x = lt[nq*4+0][ml];
    o.y = lt[nq*4+1][ml];
    o.z = lt[nq*4+2][ml];
    o.w = lt[nq*4+3][ml];
    *(ushort4*)&HT[(size_t)c*NN + (size_t)(m0+ml)*2048 + n0 + nq*4] = o;
  }
}

// ---------------- hw = h @ gcn_w  (f32), 128 blocks x 16 rows ----------------
__global__ __launch_bounds__(256)
void k_hw(const float* __restrict__ h, const float* __restrict__ W, float* __restrict__ hw){
  __shared__ float lh[16][256];
  int t = threadIdx.x;
  int n0 = blockIdx.x * 16;
  for (int idx = t; idx < 16*256; idx += 256)
    lh[idx >> 8][idx & 255] = h[(size_t)(n0 + (idx>>8))*256 + (idx&255)];
  __syncthreads();
  int d = t & 127, half = t >> 7;
  float acc[8];
  #pragma unroll
  for (int nn=0;nn<8;nn++) acc[nn] = 0.f;
  for (int k=0;k<256;k++){
    float wv = W[(size_t)k*128 + d];
    #pragma unroll
    for (int nn=0;nn<8;nn++) acc[nn] += lh[half*8+nn][k]*wv;
  }
  #pragma unroll
  for (int nn=0;nn<8;nn++) hw[(size_t)(n0 + half*8 + nn)*128 + d] = acc[nn];
}

// ---------------- PT[c][d][n] = bf16(rsqrt(max(rowsum,1)) * hw[n][d]) ----------------
__global__ void k_pt(const float* __restrict__ hw, const float* __restrict__ rowsum,
                     u16* __restrict__ PT){
  int t = threadIdx.x;
  int n = blockIdx.x * 64 + (t & 63);
  int c = blockIdx.y;
  float dv = rsqrtf(fmaxf(rowsum[c*2048 + n], 1.0f));
  for (int d = t >> 6; d < 128; d += 4)
    PT[((size_t)c*128 + d)*2048 + n] = f2b(dv * hw[(size_t)n*128 + d]);
}

// ------- GEMM3 split-K=8 (2-barrier loop), partial f32 buffers: aggp = HT @ PT^T ------
__global__ __launch_bounds__(256, 2)
void k_gemm3(const u16* __restrict__ A, const u16* __restrict__ Bt, float* __restrict__ Cp){
  __shared__ u16 lA[128*64];
  __shared__ u16 lB[128*64];
  const int tid = threadIdx.x;
  const int bm = blockIdx.x, bk = blockIdx.y, cc = blockIdx.z;
  const u16* __restrict__ Ab = A + (size_t)cc*NN + (size_t)(bm*128)*2048 + bk*256;
  const u16* __restrict__ Bb = Bt + (size_t)cc*(128*2048) + bk*256;
  float* __restrict__ Cb = Cp + ((size_t)bk*2 + cc)*2048*128 + (size_t)(bm*128)*128;
  const int wid = tid >> 6, lane = tid & 63;
  const int wr = wid >> 1, wc = wid & 1;
  const int fl = lane & 15, fk = (lane >> 4) << 3;
  const int srow = (wid << 3) + (lane >> 3);
  const int scol = (lane & 7) << 3;

  f32x4 acc[4][4];
  const f32x4 zero = {0.f,0.f,0.f,0.f};
  #pragma unroll
  for (int i=0;i<4;i++)
    #pragma unroll
    for (int jj=0;jj<4;jj++) acc[i][jj] = zero;

  for (int k0 = 0; k0 < 256; k0 += 64){
    #pragma unroll
    for (int it = 0; it < 4; ++it){
      int r = it*32 + srow;
      __builtin_amdgcn_global_load_lds(
        (const __attribute__((address_space(1))) void*)(Ab + (size_t)r*2048 + k0 + scol),
        (__attribute__((address_space(3))) void*)(&lA[(it*32 + (wid<<3))*64]), 16, 0, 0);
      __builtin_amdgcn_global_load_lds(
        (const __attribute__((address_space(1))) void*)(Bb + (size_t)r*2048 + k0 + scol),
        (__attribute__((address_space(3))) void*)(&lB[(it*32 + (wid<<3))*64]), 16, 0, 0);
    }
    __syncthreads();
    #pragma unroll
    for (int ks = 0; ks < 2; ++ks){
      bf16x8 af[4], bfr[4];
      #pragma unroll
      for (int mi=0;mi<4;mi++)
        af[mi] = *reinterpret_cast<const bf16x8*>(&lA[(wr*64 + mi*16 + fl)*64 + ks*32 + fk]);
      #pragma unroll
      for (int ni=0;ni<4;ni++)
        bfr[ni] = *reinterpret_cast<const bf16x8*>(&lB[(wc*64 + ni*16 + fl)*64 + ks*32 + fk]);
      #pragma unroll
      for (int mi=0;mi<4;mi++)
        #pragma unroll
        for (int ni=0;ni<4;ni++)
          acc[mi][ni] = __builtin_amdgcn_mfma_f32_16x16x32_bf16(af[mi], bfr[ni], acc[mi][ni], 0, 0, 0);
    }
    __syncthreads();
  }
  const int rbase = (lane >> 4) << 2;
  #pragma unroll
  for (int mi=0;mi<4;mi++)
    #pragma unroll
    for (int ni=0;ni<4;ni++)
      #pragma unroll
      for (int r=0;r<4;r++)
        Cb[(size_t)(wr*64 + mi*16 + rbase + r)*128 + wc*64 + ni*16 + fl] = acc[mi][ni][r];
}

// -------- head: Xc = relu(sum_p aggp + gb); out = relu(Xc@W1+b1)@W2+b2 ----------------
// 128 blocks x 16 rows
__global__ __launch_bounds__(256)
void k_head(const float* __restrict__ aggp, const float* __restrict__ gb,
            const float* __restrict__ W1, const float* __restrict__ b1,
            const float* __restrict__ W2, const float* __restrict__ b2,
            float* __restrict__ out){
  __shared__ float lx[16][256];
  __shared__ float lt[16][132];
  int t = threadIdx.x;
  int n0 = blockIdx.x * 16;
  for (int idx = t; idx < 1024; idx += 256){
    int row = idx >> 6;
    int q = idx & 63;
    int c = q >> 5, d4 = (q & 31) * 4;
    float4 s = *(const float4*)&gb[d4];
    #pragma unroll
    for (int p=0;p<8;p++){
      const float4 v = *(const float4*)&aggp[(((size_t)p*2 + c)*2048 + n0 + row)*128 + d4];
      s.x += v.x; s.y += v.y; s.z += v.z; s.w += v.w;
    }
    s.x = fmaxf(s.x,0.f); s.y = fmaxf(s.y,0.f); s.z = fmaxf(s.z,0.f); s.w = fmaxf(s.w,0.f);
    *(float4*)&lx[row][c*128 + d4] = s;
  }
  __syncthreads();
  int d = t & 127, half = t >> 7;
  float acc[8];
  #pragma unroll
  for (int nn=0;nn<8;nn++) acc[nn] = 0.f;
  for (int k=0;k<256;k++){
    float wv = W1[(size_t)k*128 + d];
    #pragma unroll
    for (int nn=0;nn<8;nn++) acc[nn] += lx[half*8+nn][k]*wv;
  }
  float bb = b1[d];
  #pragma unroll
  for (int nn=0;nn<8;nn++){
    float v = acc[nn] + bb;
    lt[half*8+nn][d] = v > 0.f ? v : 0.f;
  }
  __syncthreads();
  {
    int row = t >> 4, q = t & 15;
    float s = b2[q];
    for (int dd=0; dd<128; dd++) s += lt[row][dd] * W2[(size_t)dd*16 + q];
    out[(size_t)(n0+row)*16 + q] = s;
  }
}

extern "C" void kernel_launch(void* const* d_in, const int* in_sizes, int n_in,
                              void* d_out, int out_size, void* d_ws, size_t ws_size,
                              hipStream_t stream){
  const float* A   = (const float*)d_in[0];
  const float* h   = (const float*)d_in[1];
  const float* w1  = (const float*)d_in[2];
  const float* w2  = (const float*)d_in[3];
  const float* wl  = (const float*)d_in[4];
  const float* gw  = (const float*)d_in[5];
  const float* gb  = (const float*)d_in[6];
  const float* l1w = (const float*)d_in[7];
  const float* l1b = (const float*)d_in[8];
  const float* l2w = (const float*)d_in[9];
  const float* l2b = (const float*)d_in[10];
  float* out = (float*)d_out;
  char* ws = (char*)d_ws;

  const size_t SZ = 2*NN*2;   // 16.78 MB (one bf16 [2][2048][2048])
  u16*  A1   = (u16*)(ws);
  u16*  A2T  = (u16*)(ws + 1*SZ);
  u16*  BT   = (u16*)(ws + 2*SZ);
  u16*  Hbf  = (u16*)(ws + 3*SZ);
  u16*  H2bf = (u16*)(ws + 4*SZ);
  u16*  HT   = (u16*)(ws + 5*SZ);
  float* aggp= (float*)(ws + 6*SZ);               // 8 x 2 x 2048 x 128 f32 = 16.78MB
  char* tail = ws + 7*SZ;
  float* hw    = (float*)tail;                    // 1MB
  u16*  PT     = (u16*)(tail + 2048*128*4);       // 1MB
  float* deg1  = (float*)(tail + 2048*128*4 + 2*128*2048*2);
  float* deg2  = deg1 + 4096;
  float* rowsum= deg2 + 4096;

  const size_t TOTAL = 7*SZ + 2048*128*4 + (size_t)2*128*2048*2 + 3*4096*4;
  if (ws_size < TOTAL){ hipMemsetAsync(d_out, 0, (size_t)out_size*4, stream); return; }

  // deg1/deg2/rowsum zeroed inside k_mix (block 0,0); no memset dispatch
  k_mix<<<dim3(32,32), 256, 0, stream>>>(A, w1, w2, wl, A1, A2T, BT, deg1);
  // H = A1 @ A2  (bf16 out, colsum -> deg1)
  k_gemm_big<<<dim3(16,16,2), 256, 0, stream>>>(A1, A2T, Hbf, deg1);
  // fold dinv1 into B operand
  k_btscale<<<4096, 256, 0, stream>>>(BT, deg1);
  // H2 = H @ B'  (bf16 out, colsum -> deg2)
  k_gemm_big<<<dim3(16,16,2), 256, 0, stream>>>(Hbf, BT, H2bf, deg2);
  // normalize + transpose + rowsum
  k_ntrans<<<dim3(32,32,2), 256, 0, stream>>>(H2bf, deg2, HT, rowsum);
  k_hw<<<128, 256, 0, stream>>>(h, gw, hw);
  k_pt<<<dim3(32,2), 256, 0, stream>>>(hw, rowsum, PT);
  // agg partials (split-K = 8)
  k_gemm3<<<dim3(16,8,2), 256, 0, stream>>>(HT, PT, aggp);
  k_head<<<128, 256, 0, stream>>>(aggp, gb, l1w, l1b, l2w, l2b, out);
}

// Round 5
// 190.138 us; speedup vs baseline: 1.2248x; 1.2248x over previous
//
#include <hip/hip_runtime.h>

typedef unsigned short u16;
typedef __attribute__((ext_vector_type(4))) float f32x4;
typedef __attribute__((ext_vector_type(8))) __bf16 bf16x8;
typedef __attribute__((ext_vector_type(8))) unsigned short us8;

#define NN (2048ull*2048ull)

__device__ __forceinline__ u16 f2b(float x){
  union { float f; unsigned u; } v; v.f = x;
  unsigned r = v.u + 0x7FFFu + ((v.u >> 16) & 1u);
  return (u16)(r >> 16);
}
__device__ __forceinline__ float b2f(u16 x){
  union { unsigned u; float f; } v; v.u = ((unsigned)x) << 16; return v.f;
}

// ---------------- fused 3-way mix of A -> A1 (row-major) + A2T, BT (transposed), bf16
//                  block(0,0) also zero-inits deg1/deg2/rowsum (replaces memset) -------
__global__ __launch_bounds__(256)
void k_mix(const float* __restrict__ A,
           const float* __restrict__ w1, const float* __restrict__ w2,
           const float* __restrict__ wl,
           u16* __restrict__ A1, u16* __restrict__ A2T, u16* __restrict__ BT,
           float* __restrict__ zbuf){
  __shared__ u16 lt[4][64][72];
  const int t = threadIdx.x;
  if (blockIdx.x == 0 && blockIdx.y == 0){
    #pragma unroll
    for (int i=0;i<48;i++) zbuf[i*256 + t] = 0.f;   // deg1,deg2,rowsum = 12288 floats
  }
  const int mq = t & 15, nr = t >> 4;
  const int n0 = blockIdx.y * 64, m0 = blockIdx.x * 64;
  float f[3][2][5];
  #pragma unroll
  for (int s=0;s<3;s++){
    const float* w = (s==0) ? w1 : (s==1) ? w2 : wl;
    #pragma unroll
    for (int c=0;c<2;c++){
      float m = -1e30f;
      #pragma unroll
      for (int e=0;e<5;e++) m = fmaxf(m, w[e*2+c]);
      float sum = 0.f;
      #pragma unroll
      for (int e=0;e<5;e++){ f[s][c][e] = __expf(w[e*2+c]-m); sum += f[s][c][e]; }
      float inv = 1.f/sum;
      #pragma unroll
      for (int e=0;e<5;e++) f[s][c][e] *= inv;
    }
  }

  #pragma unroll
  for (int rr=0; rr<4; ++rr){
    const int nl = nr*4 + rr;
    const size_t off = (size_t)(n0+nl)*2048 + m0 + mq*4;
    float4 a0 = *(const float4*)&A[off];
    float4 a1 = *(const float4*)&A[NN + off];
    float4 a2 = *(const float4*)&A[2*NN + off];
    float4 a3 = *(const float4*)&A[3*NN + off];
    float4 a4 = *(const float4*)&A[4*NN + off];
    float ax[4][5] = {{a0.x,a1.x,a2.x,a3.x,a4.x},
                      {a0.y,a1.y,a2.y,a3.y,a4.y},
                      {a0.z,a1.z,a2.z,a3.z,a4.z},
                      {a0.w,a1.w,a2.w,a3.w,a4.w}};
    #pragma unroll
    for (int c=0;c<2;c++){
      ushort4 o1, o2, o3;
      #pragma unroll
      for (int j=0;j<4;j++){
        float s1=0.f,s2=0.f,s3=0.f;
        #pragma unroll
        for (int e=0;e<5;e++){
          s1 += ax[j][e]*f[0][c][e];
          s2 += ax[j][e]*f[1][c][e];
          s3 += ax[j][e]*f[2][c][e];
        }
        ((u16*)&o1)[j] = f2b(s1);
        ((u16*)&o2)[j] = f2b(s2);
        ((u16*)&o3)[j] = f2b(s3);
      }
      *(ushort4*)&A1[(size_t)c*NN + off] = o1;
      *(ushort4*)&lt[c][nl][mq*4] = o2;
      *(ushort4*)&lt[2+c][nl][mq*4] = o3;
    }
  }
  __syncthreads();
  const int nq = t & 15, mr = t >> 4;
  #pragma unroll
  for (int s=0;s<4;s++){
    u16* __restrict__ dst = (s<2) ? A2T : BT;
    const int c = s & 1;
    #pragma unroll
    for (int rr=0;rr<4;rr++){
      const int ml = mr*4 + rr;
      ushort4 o;
      o.x = lt[s][nq*4+0][ml];
      o.y = lt[s][nq*4+1][ml];
      o.z = lt[s][nq*4+2][ml];
      o.w = lt[s][nq*4+3][ml];
      *(ushort4*)&dst[(size_t)c*NN + (size_t)(m0+ml)*2048 + n0 + nq*4] = o;
    }
  }
}

// ------- big bt-GEMM (m97 2-barrier single-buffer loop, BK=64): C = A @ Bt^T (bf16 out)
//         + fused column sums. TRANS: store C transposed (C^T row-major). --------------
template<bool TRANS>
__global__ __launch_bounds__(256, 2)
void k_gemm_big(const u16* __restrict__ A, const u16* __restrict__ Bt,
                u16* __restrict__ C, float* __restrict__ deg){
  __shared__ u16 lA[128*64];
  __shared__ u16 lB[128*64];
  const int tid = threadIdx.x;
  const int bm = blockIdx.x, bn = blockIdx.y, cc = blockIdx.z;
  const u16* __restrict__ Ab = A + (size_t)cc*NN + (size_t)(bm*128)*2048;
  const u16* __restrict__ Bb = Bt + (size_t)cc*NN + (size_t)(bn*128)*2048;
  const int wid = tid >> 6, lane = tid & 63;
  const int wr = wid >> 1, wc = wid & 1;
  const int fl = lane & 15, fk = (lane >> 4) << 3;
  const int srow = (wid << 3) + (lane >> 3);
  const int scol = (lane & 7) << 3;

  f32x4 acc[4][4];
  const f32x4 zero = {0.f,0.f,0.f,0.f};
  #pragma unroll
  for (int i=0;i<4;i++)
    #pragma unroll
    for (int jj=0;jj<4;jj++) acc[i][jj] = zero;

  for (int k0 = 0; k0 < 2048; k0 += 64){
    #pragma unroll
    for (int it = 0; it < 4; ++it){
      int r = it*32 + srow;
      __builtin_amdgcn_global_load_lds(
        (const __attribute__((address_space(1))) void*)(Ab + (size_t)r*2048 + k0 + scol),
        (__attribute__((address_space(3))) void*)(&lA[(it*32 + (wid<<3))*64]), 16, 0, 0);
      __builtin_amdgcn_global_load_lds(
        (const __attribute__((address_space(1))) void*)(Bb + (size_t)r*2048 + k0 + scol),
        (__attribute__((address_space(3))) void*)(&lB[(it*32 + (wid<<3))*64]), 16, 0, 0);
    }
    __syncthreads();
    #pragma unroll
    for (int ks = 0; ks < 2; ++ks){
      bf16x8 af[4], bfr[4];
      #pragma unroll
      for (int mi=0;mi<4;mi++)
        af[mi] = *reinterpret_cast<const bf16x8*>(&lA[(wr*64 + mi*16 + fl)*64 + ks*32 + fk]);
      #pragma unroll
      for (int ni=0;ni<4;ni++)
        bfr[ni] = *reinterpret_cast<const bf16x8*>(&lB[(wc*64 + ni*16 + fl)*64 + ks*32 + fk]);
      #pragma unroll
      for (int mi=0;mi<4;mi++)
        #pragma unroll
        for (int ni=0;ni<4;ni++)
          acc[mi][ni] = __builtin_amdgcn_mfma_f32_16x16x32_bf16(af[mi], bfr[ni], acc[mi][ni], 0, 0, 0);
    }
    __syncthreads();
  }

  // fused column sums: deg[c][col] += sum over this block's 128 rows
  #pragma unroll
  for (int ni=0; ni<4; ++ni){
    float cs = 0.f;
    #pragma unroll
    for (int mi=0;mi<4;mi++)
      #pragma unroll
      for (int r=0;r<4;r++) cs += acc[mi][ni][r];
    cs += __shfl_xor(cs, 16);
    cs += __shfl_xor(cs, 32);
    if (lane < 16)
      atomicAdd(&deg[cc*2048 + bn*128 + wc*64 + ni*16 + fl], cs);
  }
  const int rbase = (lane >> 4) << 2;
  if (!TRANS){
    // row-major bf16 C store
    u16* __restrict__ Cb = C + (size_t)cc*NN + (size_t)(bm*128 + wr*64)*2048 + bn*128 + wc*64;
    #pragma unroll
    for (int mi=0;mi<4;mi++)
      #pragma unroll
      for (int ni=0;ni<4;ni++)
        #pragma unroll
        for (int r=0;r<4;r++)
          Cb[(size_t)(mi*16 + rbase + r)*2048 + ni*16 + fl] = f2b(acc[mi][ni][r]);
  } else {
    // transposed store: CT[col][row], r is contiguous -> 8B ushort4 per (mi,ni)
    u16* __restrict__ Cb = C + (size_t)cc*NN + (size_t)(bn*128 + wc*64)*2048 + bm*128 + wr*64;
    #pragma unroll
    for (int ni=0;ni<4;ni++)
      #pragma unroll
      for (int mi=0;mi<4;mi++){
        ushort4 o;
        o.x = f2b(acc[mi][ni][0]); o.y = f2b(acc[mi][ni][1]);
        o.z = f2b(acc[mi][ni][2]); o.w = f2b(acc[mi][ni][3]);
        *(ushort4*)&Cb[(size_t)(ni*16 + fl)*2048 + mi*16 + rbase] = o;
      }
  }
}

// ---------------- BT *= dinv1[k] in place ----------------
__global__ void k_btscale(u16* __restrict__ BT, const float* __restrict__ deg){
  size_t idx = (size_t)blockIdx.x*256 + threadIdx.x;   // 2*NN/8 = 1,048,576 total
  int c  = (int)(idx >> 19);
  int k8 = ((int)(idx & 255)) * 8;
  us8 v = ((const us8*)BT)[idx];
  #pragma unroll
  for (int j=0;j<8;j++){
    float d = deg[c*2048 + k8 + j];
    float di = d > 0.f ? 1.f/d : 0.f;
    v[j] = f2b(b2f(v[j]) * di);
  }
  ((us8*)BT)[idx] = v;
}

// -------- rowsum[c][n] = sum_m HT[c][m][n] * dinv2[c][m]  (dout source) ---------------
__global__ __launch_bounds__(256)
void k_wcolsum(const u16* __restrict__ HT, const float* __restrict__ deg2,
               float* __restrict__ rowsum){
  __shared__ float sdi[128];
  const int t = threadIdx.x;
  const int n = blockIdx.x * 256 + t;
  const int m0 = blockIdx.y * 128;
  const int c = blockIdx.z;
  if (t < 128){
    float d = deg2[c*2048 + m0 + t];
    sdi[t] = d > 0.f ? 1.f/d : 0.f;
  }
  __syncthreads();
  const u16* __restrict__ p = HT + (size_t)c*NN + (size_t)m0*2048 + n;
  float s = 0.f;
  #pragma unroll 4
  for (int m=0;m<128;m++)
    s += b2f(p[(size_t)m*2048]) * sdi[m];
  atomicAdd(&rowsum[c*2048 + n], s);
}

// ---------------- hw = h @ gcn_w  (f32), 128 blocks x 16 rows ----------------
__global__ __launch_bounds__(256)
void k_hw(const float* __restrict__ h, const float* __restrict__ W, float* __restrict__ hw){
  __shared__ float lh[16][256];
  int t = threadIdx.x;
  int n0 = blockIdx.x * 16;
  for (int idx = t; idx < 16*256; idx += 256)
    lh[idx >> 8][idx & 255] = h[(size_t)(n0 + (idx>>8))*256 + (idx&255)];
  __syncthreads();
  int d = t & 127, half = t >> 7;
  float acc[8];
  #pragma unroll
  for (int nn=0;nn<8;nn++) acc[nn] = 0.f;
  for (int k=0;k<256;k++){
    float wv = W[(size_t)k*128 + d];
    #pragma unroll
    for (int nn=0;nn<8;nn++) acc[nn] += lh[half*8+nn][k]*wv;
  }
  #pragma unroll
  for (int nn=0;nn<8;nn++) hw[(size_t)(n0 + half*8 + nn)*128 + d] = acc[nn];
}

// ---------------- PT[c][d][n] = bf16(rsqrt(max(rowsum,1)) * hw[n][d]) ----------------
__global__ void k_pt(const float* __restrict__ hw, const float* __restrict__ rowsum,
                     u16* __restrict__ PT){
  int t = threadIdx.x;
  int n = blockIdx.x * 64 + (t & 63);
  int c = blockIdx.y;
  float dv = rsqrtf(fmaxf(rowsum[c*2048 + n], 1.0f));
  for (int d = t >> 6; d < 128; d += 4)
    PT[((size_t)c*128 + d)*2048 + n] = f2b(dv * hw[(size_t)n*128 + d]);
}

// ------- GEMM3 split-K=8 (2-barrier loop), partial f32 buffers: aggp = HT @ PT^T ------
__global__ __launch_bounds__(256, 2)
void k_gemm3(const u16* __restrict__ A, const u16* __restrict__ Bt, float* __restrict__ Cp){
  __shared__ u16 lA[128*64];
  __shared__ u16 lB[128*64];
  const int tid = threadIdx.x;
  const int bm = blockIdx.x, bk = blockIdx.y, cc = blockIdx.z;
  const u16* __restrict__ Ab = A + (size_t)cc*NN + (size_t)(bm*128)*2048 + bk*256;
  const u16* __restrict__ Bb = Bt + (size_t)cc*(128*2048) + bk*256;
  float* __restrict__ Cb = Cp + ((size_t)bk*2 + cc)*2048*128 + (size_t)(bm*128)*128;
  const int wid = tid >> 6, lane = tid & 63;
  const int wr = wid >> 1, wc = wid & 1;
  const int fl = lane & 15, fk = (lane >> 4) << 3;
  const int srow = (wid << 3) + (lane >> 3);
  const int scol = (lane & 7) << 3;

  f32x4 acc[4][4];
  const f32x4 zero = {0.f,0.f,0.f,0.f};
  #pragma unroll
  for (int i=0;i<4;i++)
    #pragma unroll
    for (int jj=0;jj<4;jj++) acc[i][jj] = zero;

  for (int k0 = 0; k0 < 256; k0 += 64){
    #pragma unroll
    for (int it = 0; it < 4; ++it){
      int r = it*32 + srow;
      __builtin_amdgcn_global_load_lds(
        (const __attribute__((address_space(1))) void*)(Ab + (size_t)r*2048 + k0 + scol),
        (__attribute__((address_space(3))) void*)(&lA[(it*32 + (wid<<3))*64]), 16, 0, 0);
      __builtin_amdgcn_global_load_lds(
        (const __attribute__((address_space(1))) void*)(Bb + (size_t)r*2048 + k0 + scol),
        (__attribute__((address_space(3))) void*)(&lB[(it*32 + (wid<<3))*64]), 16, 0, 0);
    }
    __syncthreads();
    #pragma unroll
    for (int ks = 0; ks < 2; ++ks){
      bf16x8 af[4], bfr[4];
      #pragma unroll
      for (int mi=0;mi<4;mi++)
        af[mi] = *reinterpret_cast<const bf16x8*>(&lA[(wr*64 + mi*16 + fl)*64 + ks*32 + fk]);
      #pragma unroll
      for (int ni=0;ni<4;ni++)
        bfr[ni] = *reinterpret_cast<const bf16x8*>(&lB[(wc*64 + ni*16 + fl)*64 + ks*32 + fk]);
      #pragma unroll
      for (int mi=0;mi<4;mi++)
        #pragma unroll
        for (int ni=0;ni<4;ni++)
          acc[mi][ni] = __builtin_amdgcn_mfma_f32_16x16x32_bf16(af[mi], bfr[ni], acc[mi][ni], 0, 0, 0);
    }
    __syncthreads();
  }
  const int rbase = (lane >> 4) << 2;
  #pragma unroll
  for (int mi=0;mi<4;mi++)
    #pragma unroll
    for (int ni=0;ni<4;ni++)
      #pragma unroll
      for (int r=0;r<4;r++)
        Cb[(size_t)(wr*64 + mi*16 + rbase + r)*128 + wc*64 + ni*16 + fl] = acc[mi][ni][r];
}

// -------- head: Xc = relu(dinv2[c,m] * sum_p aggp + gb); out = relu(Xc@W1+b1)@W2+b2 ---
// 128 blocks x 16 rows
__global__ __launch_bounds__(256)
void k_head(const float* __restrict__ aggp, const float* __restrict__ deg2,
            const float* __restrict__ gb,
            const float* __restrict__ W1, const float* __restrict__ b1,
            const float* __restrict__ W2, const float* __restrict__ b2,
            float* __restrict__ out){
  __shared__ float lx[16][256];
  __shared__ float lt[16][132];
  int t = threadIdx.x;
  int n0 = blockIdx.x * 16;
  for (int idx = t; idx < 1024; idx += 256){
    int row = idx >> 6;
    int q = idx & 63;
    int c = q >> 5, d4 = (q & 31) * 4;
    float dg = deg2[c*2048 + n0 + row];
    float di = dg > 0.f ? 1.f/dg : 0.f;
    float4 s = {0.f,0.f,0.f,0.f};
    #pragma unroll
    for (int p=0;p<8;p++){
      const float4 v = *(const float4*)&aggp[(((size_t)p*2 + c)*2048 + n0 + row)*128 + d4];
      s.x += v.x; s.y += v.y; s.z += v.z; s.w += v.w;
    }
    const float4 bv = *(const float4*)&gb[d4];
    s.x = fmaxf(s.x*di + bv.x, 0.f); s.y = fmaxf(s.y*di + bv.y, 0.f);
    s.z = fmaxf(s.z*di + bv.z, 0.f); s.w = fmaxf(s.w*di + bv.w, 0.f);
    *(float4*)&lx[row][c*128 + d4] = s;
  }
  __syncthreads();
  int d = t & 127, half = t >> 7;
  float acc[8];
  #pragma unroll
  for (int nn=0;nn<8;nn++) acc[nn] = 0.f;
  for (int k=0;k<256;k++){
    float wv = W1[(size_t)k*128 + d];
    #pragma unroll
    for (int nn=0;nn<8;nn++) acc[nn] += lx[half*8+nn][k]*wv;
  }
  float bb = b1[d];
  #pragma unroll
  for (int nn=0;nn<8;nn++){
    float v = acc[nn] + bb;
    lt[half*8+nn][d] = v > 0.f ? v : 0.f;
  }
  __syncthreads();
  {
    int row = t >> 4, q = t & 15;
    float s = b2[q];
    for (int dd=0; dd<128; dd++) s += lt[row][dd] * W2[(size_t)dd*16 + q];
    out[(size_t)(n0+row)*16 + q] = s;
  }
}

extern "C" void kernel_launch(void* const* d_in, const int* in_sizes, int n_in,
                              void* d_out, int out_size, void* d_ws, size_t ws_size,
                              hipStream_t stream){
  const float* A   = (const float*)d_in[0];
  const float* h   = (const float*)d_in[1];
  const float* w1  = (const float*)d_in[2];
  const float* w2  = (const float*)d_in[3];
  const float* wl  = (const float*)d_in[4];
  const float* gw  = (const float*)d_in[5];
  const float* gb  = (const float*)d_in[6];
  const float* l1w = (const float*)d_in[7];
  const float* l1b = (const float*)d_in[8];
  const float* l2w = (const float*)d_in[9];
  const float* l2b = (const float*)d_in[10];
  float* out = (float*)d_out;
  char* ws = (char*)d_ws;

  const size_t SZ = 2*NN*2;   // 16.78 MB (one bf16 [2][2048][2048])
  u16*  A1   = (u16*)(ws);
  u16*  A2T  = (u16*)(ws + 1*SZ);
  u16*  BT   = (u16*)(ws + 2*SZ);
  u16*  Hbf  = (u16*)(ws + 3*SZ);
  u16*  HT   = (u16*)(ws + 4*SZ);        // H2^T, raw (dinv2 NOT applied)
  float* aggp= (float*)(ws + 5*SZ);      // 8 x 2 x 2048 x 128 f32 = 16.78MB
  char* tail = ws + 6*SZ;
  float* hw    = (float*)tail;                    // 1MB
  u16*  PT     = (u16*)(tail + 2048*128*4);       // 1MB
  float* deg1  = (float*)(tail + 2048*128*4 + 2*128*2048*2);
  float* deg2  = deg1 + 4096;
  float* rowsum= deg2 + 4096;

  const size_t TOTAL = 6*SZ + 2048*128*4 + (size_t)2*128*2048*2 + 3*4096*4;
  if (ws_size < TOTAL){ hipMemsetAsync(d_out, 0, (size_t)out_size*4, stream); return; }

  // deg1/deg2/rowsum zeroed inside k_mix (block 0,0); no memset dispatch
  k_mix<<<dim3(32,32), 256, 0, stream>>>(A, w1, w2, wl, A1, A2T, BT, deg1);
  // H = A1 @ A2  (bf16 out, colsum -> deg1)
  k_gemm_big<false><<<dim3(16,16,2), 256, 0, stream>>>(A1, A2T, Hbf, deg1);
  // fold dinv1 into B operand
  k_btscale<<<4096, 256, 0, stream>>>(BT, deg1);
  // H2^T = (H @ B')^T directly (bf16 out, colsum -> deg2)
  k_gemm_big<true><<<dim3(16,16,2), 256, 0, stream>>>(Hbf, BT, HT, deg2);
  // dout source: rowsum[c][n] = sum_m HT[c][m][n]*dinv2[c][m]
  k_wcolsum<<<dim3(8,16,2), 256, 0, stream>>>(HT, deg2, rowsum);
  k_hw<<<128, 256, 0, stream>>>(h, gw, hw);
  k_pt<<<dim3(32,2), 256, 0, stream>>>(hw, rowsum, PT);
  // agg partials (split-K = 8) on RAW HT; dinv2 applied in k_head
  k_gemm3<<<dim3(16,8,2), 256, 0, stream>>>(HT, PT, aggp);
  k_head<<<128, 256, 0, stream>>>(aggp, deg2, gb, l1w, l1b, l2w, l2b, out);
}

// Round 6
// 174.503 us; speedup vs baseline: 1.3345x; 1.0896x over previous
//
#include <hip/hip_runtime.h>

typedef unsigned short u16;
typedef __attribute__((ext_vector_type(4))) float f32x4;
typedef __attribute__((ext_vector_type(8))) __bf16 bf16x8;
typedef __attribute__((ext_vector_type(8))) unsigned short us8;

#define NN (2048ull*2048ull)

__device__ __forceinline__ u16 f2b(float x){
  union { float f; unsigned u; } v; v.f = x;
  unsigned r = v.u + 0x7FFFu + ((v.u >> 16) & 1u);
  return (u16)(r >> 16);
}
__device__ __forceinline__ float b2f(u16 x){
  union { unsigned u; float f; } v; v.u = ((unsigned)x) << 16; return v.f;
}

// ---------------- fused 3-way mix of A -> A1 (row-major) + A2T, BT (transposed), bf16
//                  block(0,0) also zero-inits deg1/deg2/rowsum (replaces memset) -------
__global__ __launch_bounds__(256)
void k_mix(const float* __restrict__ A,
           const float* __restrict__ w1, const float* __restrict__ w2,
           const float* __restrict__ wl,
           u16* __restrict__ A1, u16* __restrict__ A2T, u16* __restrict__ BT,
           float* __restrict__ zbuf){
  __shared__ u16 lt[4][64][72];
  const int t = threadIdx.x;
  if (blockIdx.x == 0 && blockIdx.y == 0){
    #pragma unroll
    for (int i=0;i<48;i++) zbuf[i*256 + t] = 0.f;   // deg1,deg2,rowsum = 12288 floats
  }
  const int mq = t & 15, nr = t >> 4;
  const int n0 = blockIdx.y * 64, m0 = blockIdx.x * 64;
  float f[3][2][5];
  #pragma unroll
  for (int s=0;s<3;s++){
    const float* w = (s==0) ? w1 : (s==1) ? w2 : wl;
    #pragma unroll
    for (int c=0;c<2;c++){
      float m = -1e30f;
      #pragma unroll
      for (int e=0;e<5;e++) m = fmaxf(m, w[e*2+c]);
      float sum = 0.f;
      #pragma unroll
      for (int e=0;e<5;e++){ f[s][c][e] = __expf(w[e*2+c]-m); sum += f[s][c][e]; }
      float inv = 1.f/sum;
      #pragma unroll
      for (int e=0;e<5;e++) f[s][c][e] *= inv;
    }
  }

  #pragma unroll
  for (int rr=0; rr<4; ++rr){
    const int nl = nr*4 + rr;
    const size_t off = (size_t)(n0+nl)*2048 + m0 + mq*4;
    float4 a0 = *(const float4*)&A[off];
    float4 a1 = *(const float4*)&A[NN + off];
    float4 a2 = *(const float4*)&A[2*NN + off];
    float4 a3 = *(const float4*)&A[3*NN + off];
    float4 a4 = *(const float4*)&A[4*NN + off];
    float ax[4][5] = {{a0.x,a1.x,a2.x,a3.x,a4.x},
                      {a0.y,a1.y,a2.y,a3.y,a4.y},
                      {a0.z,a1.z,a2.z,a3.z,a4.z},
                      {a0.w,a1.w,a2.w,a3.w,a4.w}};
    #pragma unroll
    for (int c=0;c<2;c++){
      ushort4 o1, o2, o3;
      #pragma unroll
      for (int j=0;j<4;j++){
        float s1=0.f,s2=0.f,s3=0.f;
        #pragma unroll
        for (int e=0;e<5;e++){
          s1 += ax[j][e]*f[0][c][e];
          s2 += ax[j][e]*f[1][c][e];
          s3 += ax[j][e]*f[2][c][e];
        }
        ((u16*)&o1)[j] = f2b(s1);
        ((u16*)&o2)[j] = f2b(s2);
        ((u16*)&o3)[j] = f2b(s3);
      }
      *(ushort4*)&A1[(size_t)c*NN + off] = o1;
      *(ushort4*)&lt[c][nl][mq*4] = o2;
      *(ushort4*)&lt[2+c][nl][mq*4] = o3;
    }
  }
  __syncthreads();
  const int nq = t & 15, mr = t >> 4;
  #pragma unroll
  for (int s=0;s<4;s++){
    u16* __restrict__ dst = (s<2) ? A2T : BT;
    const int c = s & 1;
    #pragma unroll
    for (int rr=0;rr<4;rr++){
      const int ml = mr*4 + rr;
      ushort4 o;
      o.x = lt[s][nq*4+0][ml];
      o.y = lt[s][nq*4+1][ml];
      o.z = lt[s][nq*4+2][ml];
      o.w = lt[s][nq*4+3][ml];
      *(ushort4*)&dst[(size_t)c*NN + (size_t)(m0+ml)*2048 + n0 + nq*4] = o;
    }
  }
}

// ------- big bt-GEMM, 256x128 tile, 8 waves, 2-deep counted-vmcnt pipeline,
//         XOR-swizzled LDS (linear dest + pre-swizzled global source + swizzled read).
//         C = A @ Bt^T (bf16 out) + fused column sums. TRANS: store C^T. --------------
template<bool TRANS>
__global__ __launch_bounds__(512, 2)
void k_gemm_big(const u16* __restrict__ A, const u16* __restrict__ Bt,
                u16* __restrict__ C, float* __restrict__ deg){
  __shared__ u16 lA[2][256*64];
  __shared__ u16 lB[2][128*64];
  const int tid = threadIdx.x;
  const int bm = blockIdx.x, bn = blockIdx.y, cc = blockIdx.z;
  const u16* __restrict__ Ab = A + (size_t)cc*NN + (size_t)(bm*256)*2048;
  const u16* __restrict__ Bb = Bt + (size_t)cc*NN + (size_t)(bn*128)*2048;
  const int wid = tid >> 6, lane = tid & 63;
  const int wr = wid >> 1, wc = wid & 1;
  const int fl = lane & 15, fkg = lane >> 4;           // fragment row / k-group
  // staging: thread covers 16B chunk; row within 64-row slice, swizzled source col
  const int srow = tid >> 3;                            // 0..63
  const int scol_sw = ((tid & 7) ^ (srow & 7)) << 3;    // source elem col (XOR chunk swizzle)
  // ds_read swizzled chunk offsets (in u16 elems) per ks
  const int csw0 = (((0*4 + fkg) ^ (fl & 7)) << 3);
  const int csw1 = (((1*4 + fkg) ^ (fl & 7)) << 3);

  f32x4 acc[4][4];
  const f32x4 zero = {0.f,0.f,0.f,0.f};
  #pragma unroll
  for (int i=0;i<4;i++)
    #pragma unroll
    for (int jj=0;jj<4;jj++) acc[i][jj] = zero;

  auto stage = [&](int buf, int k0){
    #pragma unroll
    for (int i=0;i<4;++i)
      __builtin_amdgcn_global_load_lds(
        (const __attribute__((address_space(1))) void*)(Ab + (size_t)(i*64 + srow)*2048 + k0 + scol_sw),
        (__attribute__((address_space(3))) void*)(&lA[buf][(i*512 + (wid<<6))<<3]), 16, 0, 0);
    #pragma unroll
    for (int i=0;i<2;++i)
      __builtin_amdgcn_global_load_lds(
        (const __attribute__((address_space(1))) void*)(Bb + (size_t)(i*64 + srow)*2048 + k0 + scol_sw),
        (__attribute__((address_space(3))) void*)(&lB[buf][(i*512 + (wid<<6))<<3]), 16, 0, 0);
  };

  auto compute = [&](const u16* __restrict__ ca, const u16* __restrict__ cb){
    bf16x8 af[2][4], bfr[2][4];
    #pragma unroll
    for (int mi=0;mi<4;mi++){
      af[0][mi] = *reinterpret_cast<const bf16x8*>(&ca[(wr*64 + mi*16 + fl)*64 + csw0]);
      af[1][mi] = *reinterpret_cast<const bf16x8*>(&ca[(wr*64 + mi*16 + fl)*64 + csw1]);
    }
    #pragma unroll
    for (int ni=0;ni<4;ni++){
      bfr[0][ni] = *reinterpret_cast<const bf16x8*>(&cb[(wc*64 + ni*16 + fl)*64 + csw0]);
      bfr[1][ni] = *reinterpret_cast<const bf16x8*>(&cb[(wc*64 + ni*16 + fl)*64 + csw1]);
    }
    __builtin_amdgcn_sched_barrier(0);
    __builtin_amdgcn_s_setprio(1);
    #pragma unroll
    for (int ks=0; ks<2; ++ks)
      #pragma unroll
      for (int mi=0;mi<4;mi++)
        #pragma unroll
        for (int ni=0;ni<4;ni++)
          acc[mi][ni] = __builtin_amdgcn_mfma_f32_16x16x32_bf16(af[ks][mi], bfr[ks][ni], acc[mi][ni], 0, 0, 0);
    __builtin_amdgcn_s_setprio(0);
    __builtin_amdgcn_sched_barrier(0);
  };

  // prologue: 2 tiles in flight
  stage(0, 0);
  stage(1, 64);
  int cur = 0;
  #pragma unroll 2
  for (int t = 0; t < 30; ++t){
    asm volatile("s_waitcnt vmcnt(6)" ::: "memory");   // tile t landed; tile t+1 in flight
    __builtin_amdgcn_sched_barrier(0);
    __builtin_amdgcn_s_barrier();
    __builtin_amdgcn_sched_barrier(0);
    compute(&lA[cur][0], &lB[cur][0]);
    __builtin_amdgcn_s_barrier();                       // all waves done reading buf[cur]
    __builtin_amdgcn_sched_barrier(0);
    stage(cur, (t+2)*64);                               // refill buf[cur] with tile t+2
    cur ^= 1;
  }
  // t = 30 (no further staging)
  asm volatile("s_waitcnt vmcnt(6)" ::: "memory");
  __builtin_amdgcn_sched_barrier(0);
  __builtin_amdgcn_s_barrier();
  __builtin_amdgcn_sched_barrier(0);
  compute(&lA[cur][0], &lB[cur][0]);
  cur ^= 1;
  // t = 31
  asm volatile("s_waitcnt vmcnt(0)" ::: "memory");
  __builtin_amdgcn_sched_barrier(0);
  __builtin_amdgcn_s_barrier();
  __builtin_amdgcn_sched_barrier(0);
  compute(&lA[cur][0], &lB[cur][0]);

  // fused column sums: deg[c][col] += sum over this block's 256 rows
  #pragma unroll
  for (int ni=0; ni<4; ++ni){
    float cs = 0.f;
    #pragma unroll
    for (int mi=0;mi<4;mi++)
      #pragma unroll
      for (int r=0;r<4;r++) cs += acc[mi][ni][r];
    cs += __shfl_xor(cs, 16);
    cs += __shfl_xor(cs, 32);
    if (lane < 16)
      atomicAdd(&deg[cc*2048 + bn*128 + wc*64 + ni*16 + fl], cs);
  }
  const int rbase = fkg << 2;
  if (!TRANS){
    u16* __restrict__ Cb = C + (size_t)cc*NN + (size_t)(bm*256 + wr*64)*2048 + bn*128 + wc*64;
    #pragma unroll
    for (int mi=0;mi<4;mi++)
      #pragma unroll
      for (int ni=0;ni<4;ni++)
        #pragma unroll
        for (int r=0;r<4;r++)
          Cb[(size_t)(mi*16 + rbase + r)*2048 + ni*16 + fl] = f2b(acc[mi][ni][r]);
  } else {
    u16* __restrict__ Cb = C + (size_t)cc*NN + (size_t)(bn*128 + wc*64)*2048 + bm*256 + wr*64;
    #pragma unroll
    for (int ni=0;ni<4;ni++)
      #pragma unroll
      for (int mi=0;mi<4;mi++){
        ushort4 o;
        o.x = f2b(acc[mi][ni][0]); o.y = f2b(acc[mi][ni][1]);
        o.z = f2b(acc[mi][ni][2]); o.w = f2b(acc[mi][ni][3]);
        *(ushort4*)&Cb[(size_t)(ni*16 + fl)*2048 + mi*16 + rbase] = o;
      }
  }
}

// ---------------- BT *= dinv1[k] in place ----------------
__global__ void k_btscale(u16* __restrict__ BT, const float* __restrict__ deg){
  size_t idx = (size_t)blockIdx.x*256 + threadIdx.x;   // 2*NN/8 = 1,048,576 total
  int c  = (int)(idx >> 19);
  int k8 = ((int)(idx & 255)) * 8;
  us8 v = ((const us8*)BT)[idx];
  #pragma unroll
  for (int j=0;j<8;j++){
    float d = deg[c*2048 + k8 + j];
    float di = d > 0.f ? 1.f/d : 0.f;
    v[j] = f2b(b2f(v[j]) * di);
  }
  ((us8*)BT)[idx] = v;
}

// -------- rowsum[c][n] = sum_m HT[c][m][n] * dinv2[c][m]  (dout source) ---------------
__global__ __launch_bounds__(256)
void k_wcolsum(const u16* __restrict__ HT, const float* __restrict__ deg2,
               float* __restrict__ rowsum){
  __shared__ float sdi[128];
  const int t = threadIdx.x;
  const int n = blockIdx.x * 256 + t;
  const int m0 = blockIdx.y * 128;
  const int c = blockIdx.z;
  if (t < 128){
    float d = deg2[c*2048 + m0 + t];
    sdi[t] = d > 0.f ? 1.f/d : 0.f;
  }
  __syncthreads();
  const u16* __restrict__ p = HT + (size_t)c*NN + (size_t)m0*2048 + n;
  float s = 0.f;
  #pragma unroll 4
  for (int m=0;m<128;m++)
    s += b2f(p[(size_t)m*2048]) * sdi[m];
  atomicAdd(&rowsum[c*2048 + n], s);
}

// ---------------- hw = h @ gcn_w  (f32), 128 blocks x 16 rows ----------------
__global__ __launch_bounds__(256)
void k_hw(const float* __restrict__ h, const float* __restrict__ W, float* __restrict__ hw){
  __shared__ float lh[16][256];
  int t = threadIdx.x;
  int n0 = blockIdx.x * 16;
  for (int idx = t; idx < 16*256; idx += 256)
    lh[idx >> 8][idx & 255] = h[(size_t)(n0 + (idx>>8))*256 + (idx&255)];
  __syncthreads();
  int d = t & 127, half = t >> 7;
  float acc[8];
  #pragma unroll
  for (int nn=0;nn<8;nn++) acc[nn] = 0.f;
  for (int k=0;k<256;k++){
    float wv = W[(size_t)k*128 + d];
    #pragma unroll
    for (int nn=0;nn<8;nn++) acc[nn] += lh[half*8+nn][k]*wv;
  }
  #pragma unroll
  for (int nn=0;nn<8;nn++) hw[(size_t)(n0 + half*8 + nn)*128 + d] = acc[nn];
}

// ---------------- PT[c][d][n] = bf16(rsqrt(max(rowsum,1)) * hw[n][d]) ----------------
__global__ void k_pt(const float* __restrict__ hw, const float* __restrict__ rowsum,
                     u16* __restrict__ PT){
  int t = threadIdx.x;
  int n = blockIdx.x * 64 + (t & 63);
  int c = blockIdx.y;
  float dv = rsqrtf(fmaxf(rowsum[c*2048 + n], 1.0f));
  for (int d = t >> 6; d < 128; d += 4)
    PT[((size_t)c*128 + d)*2048 + n] = f2b(dv * hw[(size_t)n*128 + d]);
}

// ------- GEMM3 split-K=8 (2-barrier loop), partial f32 buffers: aggp = HT @ PT^T ------
__global__ __launch_bounds__(256, 2)
void k_gemm3(const u16* __restrict__ A, const u16* __restrict__ Bt, float* __restrict__ Cp){
  __shared__ u16 lA[128*64];
  __shared__ u16 lB[128*64];
  const int tid = threadIdx.x;
  const int bm = blockIdx.x, bk = blockIdx.y, cc = blockIdx.z;
  const u16* __restrict__ Ab = A + (size_t)cc*NN + (size_t)(bm*128)*2048 + bk*256;
  const u16* __restrict__ Bb = Bt + (size_t)cc*(128*2048) + bk*256;
  float* __restrict__ Cb = Cp + ((size_t)bk*2 + cc)*2048*128 + (size_t)(bm*128)*128;
  const int wid = tid >> 6, lane = tid & 63;
  const int wr = wid >> 1, wc = wid & 1;
  const int fl = lane & 15, fk = (lane >> 4) << 3;
  const int srow = (wid << 3) + (lane >> 3);
  const int scol = (lane & 7) << 3;

  f32x4 acc[4][4];
  const f32x4 zero = {0.f,0.f,0.f,0.f};
  #pragma unroll
  for (int i=0;i<4;i++)
    #pragma unroll
    for (int jj=0;jj<4;jj++) acc[i][jj] = zero;

  for (int k0 = 0; k0 < 256; k0 += 64){
    #pragma unroll
    for (int it = 0; it < 4; ++it){
      int r = it*32 + srow;
      __builtin_amdgcn_global_load_lds(
        (const __attribute__((address_space(1))) void*)(Ab + (size_t)r*2048 + k0 + scol),
        (__attribute__((address_space(3))) void*)(&lA[(it*32 + (wid<<3))*64]), 16, 0, 0);
      __builtin_amdgcn_global_load_lds(
        (const __attribute__((address_space(1))) void*)(Bb + (size_t)r*2048 + k0 + scol),
        (__attribute__((address_space(3))) void*)(&lB[(it*32 + (wid<<3))*64]), 16, 0, 0);
    }
    __syncthreads();
    #pragma unroll
    for (int ks = 0; ks < 2; ++ks){
      bf16x8 af[4], bfr[4];
      #pragma unroll
      for (int mi=0;mi<4;mi++)
        af[mi] = *reinterpret_cast<const bf16x8*>(&lA[(wr*64 + mi*16 + fl)*64 + ks*32 + fk]);
      #pragma unroll
      for (int ni=0;ni<4;ni++)
        bfr[ni] = *reinterpret_cast<const bf16x8*>(&lB[(wc*64 + ni*16 + fl)*64 + ks*32 + fk]);
      #pragma unroll
      for (int mi=0;mi<4;mi++)
        #pragma unroll
        for (int ni=0;ni<4;ni++)
          acc[mi][ni] = __builtin_amdgcn_mfma_f32_16x16x32_bf16(af[mi], bfr[ni], acc[mi][ni], 0, 0, 0);
    }
    __syncthreads();
  }
  const int rbase = (lane >> 4) << 2;
  #pragma unroll
  for (int mi=0;mi<4;mi++)
    #pragma unroll
    for (int ni=0;ni<4;ni++)
      #pragma unroll
      for (int r=0;r<4;r++)
        Cb[(size_t)(wr*64 + mi*16 + rbase + r)*128 + wc*64 + ni*16 + fl] = acc[mi][ni][r];
}

// -------- head: Xc = relu(dinv2[c,m] * sum_p aggp + gb); out = relu(Xc@W1+b1)@W2+b2 ---
// 128 blocks x 16 rows
__global__ __launch_bounds__(256)
void k_head(const float* __restrict__ aggp, const float* __restrict__ deg2,
            const float* __restrict__ gb,
            const float* __restrict__ W1, const float* __restrict__ b1,
            const float* __restrict__ W2, const float* __restrict__ b2,
            float* __restrict__ out){
  __shared__ float lx[16][256];
  __shared__ float lt[16][132];
  int t = threadIdx.x;
  int n0 = blockIdx.x * 16;
  for (int idx = t; idx < 1024; idx += 256){
    int row = idx >> 6;
    int q = idx & 63;
    int c = q >> 5, d4 = (q & 31) * 4;
    float dg = deg2[c*2048 + n0 + row];
    float di = dg > 0.f ? 1.f/dg : 0.f;
    float4 s = {0.f,0.f,0.f,0.f};
    #pragma unroll
    for (int p=0;p<8;p++){
      const float4 v = *(const float4*)&aggp[(((size_t)p*2 + c)*2048 + n0 + row)*128 + d4];
      s.x += v.x; s.y += v.y; s.z += v.z; s.w += v.w;
    }
    const float4 bv = *(const float4*)&gb[d4];
    s.x = fmaxf(s.x*di + bv.x, 0.f); s.y = fmaxf(s.y*di + bv.y, 0.f);
    s.z = fmaxf(s.z*di + bv.z, 0.f); s.w = fmaxf(s.w*di + bv.w, 0.f);
    *(float4*)&lx[row][c*128 + d4] = s;
  }
  __syncthreads();
  int d = t & 127, half = t >> 7;
  float acc[8];
  #pragma unroll
  for (int nn=0;nn<8;nn++) acc[nn] = 0.f;
  for (int k=0;k<256;k++){
    float wv = W1[(size_t)k*128 + d];
    #pragma unroll
    for (int nn=0;nn<8;nn++) acc[nn] += lx[half*8+nn][k]*wv;
  }
  float bb = b1[d];
  #pragma unroll
  for (int nn=0;nn<8;nn++){
    float v = acc[nn] + bb;
    lt[half*8+nn][d] = v > 0.f ? v : 0.f;
  }
  __syncthreads();
  {
    int row = t >> 4, q = t & 15;
    float s = b2[q];
    for (int dd=0; dd<128; dd++) s += lt[row][dd] * W2[(size_t)dd*16 + q];
    out[(size_t)(n0+row)*16 + q] = s;
  }
}

extern "C" void kernel_launch(void* const* d_in, const int* in_sizes, int n_in,
                              void* d_out, int out_size, void* d_ws, size_t ws_size,
                              hipStream_t stream){
  const float* A   = (const float*)d_in[0];
  const float* h   = (const float*)d_in[1];
  const float* w1  = (const float*)d_in[2];
  const float* w2  = (const float*)d_in[3];
  const float* wl  = (const float*)d_in[4];
  const float* gw  = (const float*)d_in[5];
  const float* gb  = (const float*)d_in[6];
  const float* l1w = (const float*)d_in[7];
  const float* l1b = (const float*)d_in[8];
  const float* l2w = (const float*)d_in[9];
  const float* l2b = (const float*)d_in[10];
  float* out = (float*)d_out;
  char* ws = (char*)d_ws;

  const size_t SZ = 2*NN*2;   // 16.78 MB (one bf16 [2][2048][2048])
  u16*  A1   = (u16*)(ws);
  u16*  A2T  = (u16*)(ws + 1*SZ);
  u16*  BT   = (u16*)(ws + 2*SZ);
  u16*  Hbf  = (u16*)(ws + 3*SZ);
  u16*  HT   = (u16*)(ws + 4*SZ);        // H2^T, raw (dinv2 NOT applied)
  float* aggp= (float*)(ws + 5*SZ);      // 8 x 2 x 2048 x 128 f32 = 16.78MB
  char* tail = ws + 6*SZ;
  float* hw    = (float*)tail;                    // 1MB
  u16*  PT     = (u16*)(tail + 2048*128*4);       // 1MB
  float* deg1  = (float*)(tail + 2048*128*4 + 2*128*2048*2);
  float* deg2  = deg1 + 4096;
  float* rowsum= deg2 + 4096;

  const size_t TOTAL = 6*SZ + 2048*128*4 + (size_t)2*128*2048*2 + 3*4096*4;
  if (ws_size < TOTAL){ hipMemsetAsync(d_out, 0, (size_t)out_size*4, stream); return; }

  // deg1/deg2/rowsum zeroed inside k_mix (block 0,0); no memset dispatch
  k_mix<<<dim3(32,32), 256, 0, stream>>>(A, w1, w2, wl, A1, A2T, BT, deg1);
  // H = A1 @ A2  (bf16 out, colsum -> deg1)
  k_gemm_big<false><<<dim3(8,16,2), 512, 0, stream>>>(A1, A2T, Hbf, deg1);
  // fold dinv1 into B operand
  k_btscale<<<4096, 256, 0, stream>>>(BT, deg1);
  // H2^T = (H @ B')^T directly (bf16 out, colsum -> deg2)
  k_gemm_big<true><<<dim3(8,16,2), 512, 0, stream>>>(Hbf, BT, HT, deg2);
  // dout source: rowsum[c][n] = sum_m HT[c][m][n]*dinv2[c][m]
  k_wcolsum<<<dim3(8,16,2), 256, 0, stream>>>(HT, deg2, rowsum);
  k_hw<<<128, 256, 0, stream>>>(h, gw, hw);
  k_pt<<<dim3(32,2), 256, 0, stream>>>(hw, rowsum, PT);
  // agg partials (split-K = 8) on RAW HT; dinv2 applied in k_head
  k_gemm3<<<dim3(16,8,2), 256, 0, stream>>>(HT, PT, aggp);
  k_head<<<128, 256, 0, stream>>>(aggp, deg2, gb, l1w, l1b, l2w, l2b, out);
}